// Round 8
// baseline (626.343 us; speedup 1.0000x reference)
//
#include <hip/hip_runtime.h>

#define HW 16384

typedef __attribute__((ext_vector_type(8))) __bf16 bf16x8;
typedef __attribute__((ext_vector_type(16))) float floatx16;
typedef __attribute__((ext_vector_type(8))) unsigned short ushort8_t;

typedef const __attribute__((address_space(1))) unsigned int gu32;
typedef __attribute__((address_space(3))) unsigned int lu32;

__device__ __forceinline__ unsigned short f2bf(float f) {
    // round-to-nearest-even fp32 -> bf16
    unsigned int u = __builtin_bit_cast(unsigned int, f);
    unsigned int r = (u + 0x7FFFu + ((u >> 16) & 1u)) >> 16;
    return (unsigned short)r;
}

__device__ __forceinline__ void gload_lds16(const void* g, void* l) {
    __builtin_amdgcn_global_load_lds((gu32*)g, (lu32*)l, 16, 0, 0);
}

// Pre-convert W to bf16 in per-kt tiles [256 rows][64 k], XOR-swizzled so the main
// kernel can global_load_lds linearly and ds_read with the same involution.
// ushort index within tile: (row*64 + kl) ^ ((row&7)<<3); tile kt base = kt*16384.
__global__ void wconv_kernel(const float* __restrict__ w, unsigned short* __restrict__ wb) {
    int i = blockIdx.x * 256 + threadIdx.x;   // 65536 elements, i = row*256 + c
    int row = i >> 8, c = i & 255;
    int kt = c >> 6, kl = c & 63;
    int idx = (row * 64 + kl) ^ ((row & 7) << 3);
    wb[kt * 16384 + idx] = f2bf(w[i]);
}

// PERSISTENT blocks: 256 blocks x 512 threads (1 block/CU). Each block stages the
// full pre-swizzled W (128 KB) to LDS ONCE, then processes 4 consecutive 256-px
// tiles of one batch with ZERO synchronization in the main loop:
//   - X: direct-to-register prefetch double-buffer (xf0/xf1), rolling across
//     tile boundaries; 32 coalesced dword loads per wave per kt stay in flight
//     under the previous iteration's compute.
//   - compute: mfma_32x32x16, 8 m-tiles (acc = 8 x f32x16), B-frag packed in-reg.
//   - epilogue per tile: lane-local lifting + fire-and-forget float2 stores
//     (never drained until kernel end).
// Lifting partners (q, q+64, q+128, q+192) = acc[mt2], acc[mt2+2], acc[mt2+4],
// acc[mt2+6] at the same reg; 32x32 C/D map: col=lane&31, row=(reg&3)+8*(reg>>2)+4*(lane>>5).
__global__ __launch_bounds__(512, 2) void fused_gemm_lift(
        const float* __restrict__ x,
        const unsigned short* __restrict__ wb,
        const float* __restrict__ lp_v,
        const float* __restrict__ hp_v,
        const float* __restrict__ lp_h,
        const float* __restrict__ hp_h,
        float* __restrict__ out) {
    __shared__ alignas(16) unsigned short wlds[65536];  // full W, 4 kt-tiles of 16384

    const int tid  = threadIdx.x;
    const int wv   = tid >> 6;
    const int lane = tid & 63;
    const int l31  = lane & 31;
    const int hi   = lane >> 5;

    const int blk = blockIdx.x;          // 0..255
    const int bb  = blk >> 4;            // batch 0..15
    const int tt0 = (blk & 15) * 4;      // first of 4 consecutive 256-px tiles

    const float* xbase = x + (size_t)bb * 256 * HW;

    // ---- stage full W once (the only barrier in the kernel) ----
    #pragma unroll
    for (int p = 0; p < 16; ++p)
        gload_lds16(wb + (size_t)(p * 512 + tid) * 8, &wlds[(p * 512 + tid) * 8]);
    __syncthreads();

    floatx16 acc[8];
    #pragma unroll
    for (int mt = 0; mt < 8; ++mt)
        #pragma unroll
        for (int e = 0; e < 16; ++e) acc[mt][e] = 0.f;

    float xf0[32], xf1[32];   // named buffers only (rule #20: no runtime indexing)

    // prefetch (tile 0, kt 0) -> xf0
    {
        const float* xp = xbase + (size_t)tt0 * 256 + wv * 32 + l31;
        #pragma unroll
        for (int jj = 0; jj < 32; ++jj) {
            int c = (jj >> 3) * 16 + hi * 8 + (jj & 7);
            xf0[jj] = xp[(size_t)c * HW];
        }
    }

    // ---- main loop: 4 tiles x 4 kt, flattened, fully unrolled, no barriers ----
    #define STEP(IT, CUR, NXT) do {                                            \
        const int tile_ = (IT) >> 2, kt_ = (IT) & 3;                           \
        if ((IT) < 15) {   /* prefetch IT+1 into NXT */                        \
            const int nt_ = ((IT) + 1) >> 2, nk_ = ((IT) + 1) & 3;             \
            const float* xp_ = xbase + (size_t)(tt0 + nt_) * 256 + wv * 32 + l31; \
            _Pragma("unroll")                                                  \
            for (int jj = 0; jj < 32; ++jj) {                                  \
                int c_ = nk_ * 64 + (jj >> 3) * 16 + hi * 8 + (jj & 7);        \
                NXT[jj] = xp_[(size_t)c_ * HW];                                \
            }                                                                  \
        }                                                                      \
        _Pragma("unroll")                                                      \
        for (int k16_ = 0; k16_ < 4; ++k16_) {                                 \
            ushort8_t u_;                                                      \
            _Pragma("unroll")                                                  \
            for (int j_ = 0; j_ < 8; ++j_) u_[j_] = f2bf(CUR[k16_ * 8 + j_]);  \
            const bf16x8 bq_ = __builtin_bit_cast(bf16x8, u_);                 \
            const int kl_ = k16_ * 16 + hi * 8;                                \
            _Pragma("unroll")                                                  \
            for (int mt_ = 0; mt_ < 8; ++mt_) {                                \
                const int row_ = mt_ * 32 + l31;                               \
                bf16x8 af_ = *reinterpret_cast<const bf16x8*>(                 \
                    &wlds[kt_ * 16384 + ((row_ * 64 + kl_) ^ ((row_ & 7) << 3))]); \
                acc[mt_] = __builtin_amdgcn_mfma_f32_32x32x16_bf16(            \
                    af_, bq_, acc[mt_], 0, 0, 0);                              \
            }                                                                  \
        }                                                                      \
        if (kt_ == 3) {   /* per-tile epilogue + acc reset */                  \
            const int px_ = (tt0 + tile_) * 256 + wv * 32 + l31;               \
            const int h_ = px_ >> 7, w_ = px_ & 127;                           \
            float* ob_ = out + (size_t)bb * 64 * 65536                         \
                             + (size_t)(2 * h_) * 256 + 2 * w_;               \
            _Pragma("unroll")                                                  \
            for (int mt2_ = 0; mt2_ < 2; ++mt2_)                               \
                _Pragma("unroll")                                              \
                for (int reg_ = 0; reg_ < 16; ++reg_) {                        \
                    const int rowl_ = (reg_ & 3) + 8 * (reg_ >> 2) + 4 * hi;   \
                    const int q_ = mt2_ * 32 + rowl_;                          \
                    const float2 lv_ = *reinterpret_cast<const float2*>(lp_v + 2 * q_); \
                    const float2 hv_ = *reinterpret_cast<const float2*>(hp_v + 2 * q_); \
                    const float2 lh_ = *reinterpret_cast<const float2*>(lp_h + 2 * q_); \
                    const float2 hh_ = *reinterpret_cast<const float2*>(hp_h + 2 * q_); \
                    const float a_  = acc[mt2_][reg_];                         \
                    const float b_  = acc[mt2_ + 2][reg_];                     \
                    const float c_  = acc[mt2_ + 4][reg_];                     \
                    const float d_  = acc[mt2_ + 6][reg_];                     \
                    const float xl0_ = lv_.x * a_ + lv_.y * b_;                \
                    const float xl1_ = hv_.x * a_ + hv_.y * b_;                \
                    const float xh0_ = lv_.x * c_ + lv_.y * d_;                \
                    const float xh1_ = hv_.x * c_ + hv_.y * d_;                \
                    float2 r0_ = make_float2(lh_.x * xl0_ + lh_.y * xh0_,      \
                                             hh_.x * xl0_ + hh_.y * xh0_);     \
                    float2 r1_ = make_float2(lh_.x * xl1_ + lh_.y * xh1_,      \
                                             hh_.x * xl1_ + hh_.y * xh1_);     \
                    float* oq_ = ob_ + (size_t)q_ * 65536;                     \
                    *reinterpret_cast<float2*>(oq_)       = r0_;               \
                    *reinterpret_cast<float2*>(oq_ + 256) = r1_;               \
                }                                                              \
            _Pragma("unroll")                                                  \
            for (int mt_ = 0; mt_ < 8; ++mt_)                                  \
                _Pragma("unroll")                                              \
                for (int e_ = 0; e_ < 16; ++e_) acc[mt_][e_] = 0.f;            \
        }                                                                      \
    } while (0)

    #pragma unroll
    for (int ith = 0; ith < 8; ++ith) {
        STEP(2 * ith,     xf0, xf1);
        STEP(2 * ith + 1, xf1, xf0);
    }
    #undef STEP
}

extern "C" void kernel_launch(void* const* d_in, const int* in_sizes, int n_in,
                              void* d_out, int out_size, void* d_ws, size_t ws_size,
                              hipStream_t stream) {
    const float* x   = (const float*)d_in[0];
    const float* w   = (const float*)d_in[1];
    const float* lpv = (const float*)d_in[2];
    const float* hpv = (const float*)d_in[3];
    const float* lph = (const float*)d_in[4];
    const float* hph = (const float*)d_in[5];
    float* outp = (float*)d_out;
    unsigned short* wbp = (unsigned short*)d_ws;   // 128 KB bf16 weights, pre-swizzled tiles

    wconv_kernel<<<dim3(256), dim3(256), 0, stream>>>(w, wbp);
    fused_gemm_lift<<<dim3(256), dim3(512), 0, stream>>>(x, wbp, lpv, hpv, lph, hph, outp);
}

// Round 9
// 143.870 us; speedup vs baseline: 4.3535x; 4.3535x over previous
//
#include <hip/hip_runtime.h>

#define HW 16384

typedef __attribute__((ext_vector_type(8))) __bf16 bf16x8;
typedef __attribute__((ext_vector_type(16))) float floatx16;
typedef __attribute__((ext_vector_type(8))) unsigned short ushort8_t;

typedef const __attribute__((address_space(1))) unsigned int gu32;
typedef __attribute__((address_space(3))) unsigned int lu32;

__device__ __forceinline__ unsigned short f2bf(float f) {
    // round-to-nearest-even fp32 -> bf16
    unsigned int u = __builtin_bit_cast(unsigned int, f);
    unsigned int r = (u + 0x7FFFu + ((u >> 16) & 1u)) >> 16;
    return (unsigned short)r;
}

__device__ __forceinline__ void gload_lds16(const void* g, void* l) {
    __builtin_amdgcn_global_load_lds((gu32*)g, (lu32*)l, 16, 0, 0);
}

// Pre-convert W to bf16 in per-kt tiles [256 rows][64 k], XOR-swizzled so the main
// kernel can global_load_lds linearly and ds_read with the same involution.
// ushort index within tile: (row*64 + kl) ^ ((row&7)<<3); tile kt base = kt*16384.
__global__ void wconv_kernel(const float* __restrict__ w, unsigned short* __restrict__ wb) {
    int i = blockIdx.x * 256 + threadIdx.x;   // 65536 elements, i = row*256 + c
    int row = i >> 8, c = i & 255;
    int kt = c >> 6, kl = c & 63;
    int idx = (row * 64 + kl) ^ ((row & 7) << 3);
    wb[kt * 16384 + idx] = f2bf(w[i]);
}

// MLP-focused design: block = 32 q-outputs (qb half) x 256 px, K=256.
// W-slice (128 rows: {g*64 + qb*32 + r}) staged to 64 KB LDS once -> 2 blocks/CU;
// acc[4] (64 VGPR) + 2x16 prefetch regs stay under the honest (512,4) 128-VGPR cap
// -> 16 waves/CU, each with 16 independent X loads in flight, ZERO in-loop barriers.
// 8 waves = 8 x 32-px windows. mfma_32x32x16; lifting partners (q,q+64,q+128,q+192)
// = acc[0..3] at the same reg (lane-local). C/D map: col=lane&31,
// row=(reg&3)+8*(reg>>2)+4*(lane>>5). Adjacent blockIdx = qb pair -> X shared via L3.
__global__ __launch_bounds__(512, 4) void fused_gemm_lift(
        const float* __restrict__ x,
        const unsigned short* __restrict__ wb,
        const float* __restrict__ lp_v,
        const float* __restrict__ hp_v,
        const float* __restrict__ lp_h,
        const float* __restrict__ hp_h,
        float* __restrict__ out) {
    __shared__ alignas(16) unsigned short wlds[32768];  // 64 KB: [4 kt][128 rs][64 k]

    const int tid  = threadIdx.x;
    const int wv   = tid >> 6;
    const int lane = tid & 63;
    const int l31  = lane & 31;
    const int hi   = lane >> 5;

    const int qb = blockIdx.x & 1;          // q half: q in [qb*32, qb*32+32)
    const int pt = (blockIdx.x >> 1) & 63;  // 256-px tile
    const int bb = blockIdx.x >> 7;         // batch

    const int px = pt * 256 + wv * 32 + l31;
    const float* xp = x + (size_t)bb * 256 * HW + px;   // this lane's pixel column

    // ---- stage W slice -> LDS (only barrier in the kernel) ----
    // slice row rs (0..127) -> global row grow = (rs&31) + qb*32 + (rs>>5)*64;
    // grow&7 == rs&7, so the wconv swizzle carries over unchanged.
    #pragma unroll
    for (int it = 0; it < 8; ++it) {
        const int f  = it * 512 + tid;          // 16B chunk index, 0..4095
        const int rs = (f >> 3) & 127;
        const int kt = f >> 10;
        const int pc = f & 7;
        const int grow = (rs & 31) + qb * 32 + (rs >> 5) * 64;
        gload_lds16(wb + (size_t)kt * 16384 + grow * 64 + pc * 8,
                    (char*)wlds + (size_t)f * 16);
    }
    __syncthreads();

    floatx16 acc[4];
    #pragma unroll
    for (int g = 0; g < 4; ++g)
        #pragma unroll
        for (int e = 0; e < 16; ++e) acc[g][e] = 0.f;

    float xf0[16], xf1[16];   // named double-buffers (no runtime indexing)

    // prefetch phase 0 (channels 0..31; lane takes hi*8+j of each 16-ch k16 group)
    #pragma unroll
    for (int j = 0; j < 16; ++j) {
        const int c = (j >> 3) * 16 + hi * 8 + (j & 7);
        xf0[j] = xp[(size_t)c * HW];
    }

    // ---- main loop: 8 phases x (prefetch 16 || 2 k16-steps x 4 MFMA), no barriers ----
    #define PHASE(PH, CUR, NXT) do {                                           \
        if ((PH) < 7) {                                                        \
            _Pragma("unroll")                                                  \
            for (int j_ = 0; j_ < 16; ++j_) {                                  \
                const int c_ = ((PH) + 1) * 32 + (j_ >> 3) * 16 + hi * 8 + (j_ & 7); \
                NXT[j_] = xp[(size_t)c_ * HW];                                 \
            }                                                                  \
        }                                                                      \
        _Pragma("unroll")                                                      \
        for (int s_ = 0; s_ < 2; ++s_) {                                       \
            ushort8_t u_;                                                      \
            _Pragma("unroll")                                                  \
            for (int j_ = 0; j_ < 8; ++j_) u_[j_] = f2bf(CUR[s_ * 8 + j_]);    \
            const bf16x8 bq_ = __builtin_bit_cast(bf16x8, u_);                 \
            const int k16_ = 2 * (PH) + s_;                                    \
            const int kt_  = k16_ >> 2;                                        \
            const int kl_  = (k16_ & 3) * 16 + hi * 8;                         \
            _Pragma("unroll")                                                  \
            for (int g_ = 0; g_ < 4; ++g_) {                                   \
                const int rs_ = g_ * 32 + l31;                                 \
                bf16x8 af_ = *reinterpret_cast<const bf16x8*>(                 \
                    &wlds[kt_ * 8192 + rs_ * 64 + (kl_ ^ ((rs_ & 7) << 3))]);  \
                acc[g_] = __builtin_amdgcn_mfma_f32_32x32x16_bf16(             \
                    af_, bq_, acc[g_], 0, 0, 0);                               \
            }                                                                  \
        } } while (0)

    PHASE(0, xf0, xf1);
    PHASE(1, xf1, xf0);
    PHASE(2, xf0, xf1);
    PHASE(3, xf1, xf0);
    PHASE(4, xf0, xf1);
    PHASE(5, xf1, xf0);
    PHASE(6, xf0, xf1);
    PHASE(7, xf1, xf0);
    #undef PHASE

    // ---- fused lifting epilogue (lane-local, fire-and-forget stores) ----
    const int h = px >> 7;
    const int w = px & 127;
    float* outbase = out + (size_t)bb * 64 * 65536 + (size_t)(2 * h) * 256 + 2 * w;
    #pragma unroll
    for (int reg = 0; reg < 16; ++reg) {
        const int rowl = (reg & 3) + 8 * (reg >> 2) + 4 * hi;
        const int q = qb * 32 + rowl;
        const float2 lv = *reinterpret_cast<const float2*>(lp_v + 2 * q);
        const float2 hv = *reinterpret_cast<const float2*>(hp_v + 2 * q);
        const float2 lh = *reinterpret_cast<const float2*>(lp_h + 2 * q);
        const float2 hh = *reinterpret_cast<const float2*>(hp_h + 2 * q);
        const float a  = acc[0][reg];
        const float b2 = acc[1][reg];
        const float c2 = acc[2][reg];
        const float d2 = acc[3][reg];
        const float xl0 = lv.x * a + lv.y * b2;   // even output row
        const float xl1 = hv.x * a + hv.y * b2;   // odd output row
        const float xh0 = lv.x * c2 + lv.y * d2;
        const float xh1 = hv.x * c2 + hv.y * d2;
        float2 r0 = make_float2(lh.x * xl0 + lh.y * xh0, hh.x * xl0 + hh.y * xh0);
        float2 r1 = make_float2(lh.x * xl1 + lh.y * xh1, hh.x * xl1 + hh.y * xh1);
        float* oq = outbase + (size_t)q * 65536;
        *reinterpret_cast<float2*>(oq)       = r0;
        *reinterpret_cast<float2*>(oq + 256) = r1;
    }
}

extern "C" void kernel_launch(void* const* d_in, const int* in_sizes, int n_in,
                              void* d_out, int out_size, void* d_ws, size_t ws_size,
                              hipStream_t stream) {
    const float* x   = (const float*)d_in[0];
    const float* w   = (const float*)d_in[1];
    const float* lpv = (const float*)d_in[2];
    const float* hpv = (const float*)d_in[3];
    const float* lph = (const float*)d_in[4];
    const float* hph = (const float*)d_in[5];
    float* outp = (float*)d_out;
    unsigned short* wbp = (unsigned short*)d_ws;   // 128 KB bf16 weights, pre-swizzled tiles

    wconv_kernel<<<dim3(256), dim3(256), 0, stream>>>(w, wbp);
    fused_gemm_lift<<<dim3(2048), dim3(512), 0, stream>>>(x, wbp, lpv, hpv, lph, hph, outp);
}